// Round 14
// baseline (229.100 us; speedup 1.0000x reference)
//
#include <hip/hip_runtime.h>
#include <cstdint>

#define BB 8192
#define TT 50
#define FF 24
#define ROWS 32
#define LOG2E 1.4426950408889634f

typedef __attribute__((ext_vector_type(8))) short short8;
typedef __attribute__((ext_vector_type(4))) float f32x4;

// sigmoid on pre-scaled input (weights carry log2e): 1/(1+2^-x).
__device__ __forceinline__ float sig2(float xs){
  return __builtin_amdgcn_rcpf(1.0f + __builtin_amdgcn_exp2f(-xs));
}

// hardware RNE bf16 pair-convert (lo=a, hi=b)
__device__ __forceinline__ unsigned cvtpk(float a, float b){
  unsigned r;
  asm("v_cvt_pk_bf16_f32 %0, %1, %2" : "=v"(r) : "v"(a), "v"(b));
  return r;
}

// single bf16 RNE -- prologue/cold paths only
__device__ __forceinline__ unsigned short rne16(float v){
  unsigned b = __float_as_uint(v);
  b += 0x7FFFu + ((b >> 16) & 1u);
  return (unsigned short)(b >> 16);
}

// LDS-only drain + barrier (R21)
__device__ __forceinline__ void phase_barrier(){
  asm volatile("s_waitcnt lgkmcnt(0)" ::: "memory");
  __builtin_amdgcn_s_barrier();
  asm volatile("" ::: "memory");
}

#define MFMA(A,B,C) __builtin_amdgcn_mfma_f32_16x16x32_bf16((A),(B),(C),0,0,0)

// Round 22: ANTI-PHASE ROLE SPLIT. R21 diagnosis: 50% of cycles all 4
// waves/SIMD stall together -- lockstep phases clump every wave onto the
// same pipe (LDS at phase start, trans at gates, serial gate tail at end).
// Split each step: M-phase {ds_read + MFMA -> park C in regs across the
// barrier} / G-phase {gates on parked C + h-write}. Row-groups rg0/rg1
// run ANTI-phased: rg's step t has M at p=2t+rg, G at p=2t+rg+1 -- so
// each phase one group uses LDS+MFMA while the other uses VALU/trans.
// 2x barriers, ~half per-phase critical chain, same issued work, math
// bit-identical (absmax invariant 1.525879e-05). Slot parities preserved
// from R21 (reads s=t&1, writes ns=(t&1)^1; rg row-ranges disjoint so
// concurrent M-reads/G-writes never alias).
// Falsifier: >=108us -> barrier floor dominates -> structural roofline.

__global__ __launch_bounds__(1024,4)
void ae_fused(
    const float* __restrict__ x,
    const float* __restrict__ W1, const float* __restrict__ U1, const float* __restrict__ b1,
    const float* __restrict__ W2, const float* __restrict__ U2, const float* __restrict__ b2,
    const float* __restrict__ W3, const float* __restrict__ U3, const float* __restrict__ b3,
    const float* __restrict__ Wd, const float* __restrict__ bd,
    float* __restrict__ out)
{
  constexpr int AS1 = 104, AS2 = 40, AS3 = 72;
  // a1 layout per row: [0..63]=h1, [64..87]=x(t), [88..103]=pad(0)
  __shared__ __align__(16) unsigned short a1[2][ROWS*AS1];
  __shared__ __align__(16) unsigned short a2[2][ROWS*AS2]; // h2(32)|pad
  __shared__ __align__(16) unsigned short a3[2][ROWS*AS3]; // h3(64)|pad

  const int tid = threadIdx.x, wave = tid>>6, lane = tid&63;
  const int quad = lane>>4, li = lane&15;
  const int w7 = wave&7, rg = wave>>3;
  const int b0 = blockIdx.x*ROWS;
  const int arow = rg*16 + li;

  const int gl = li & 3;                       // gate row this lane packs
  const float scl = (gl==2) ? 1.0f : LOG2E;    // g(relu) unscaled

  // ---- L1 weight A-frags (single bf16 RNE, scaled, reordered k) ----
  short8 A1w[2][3];
  f32x4 bi1[2];
#pragma unroll
  for (int tp=0; tp<2; ++tp){
    const int zc = gl*64 + 8*w7 + 2*(li>>2) + tp;
#pragma unroll
    for (int ks=0; ks<3; ++ks){
      short8 v1;
#pragma unroll
      for (int j=0; j<8; ++j){
        const int kk = quad*8 + j;
        float w;
        if (ks < 2) w = U1[(ks*32+kk)*256+zc];
        else        w = (kk<24) ? W1[kk*256+zc] : 0.f;
        v1[j] = (short)rne16(w*scl);
      }
      A1w[tp][ks]=v1;
    }
#pragma unroll
    for (int i2=0;i2<4;++i2)
      bi1[tp][i2] = b1[i2*64 + 8*w7 + 2*quad + tp] * ((i2==2)?1.0f:LOG2E);
  }
  // ---- L2 weight A-frags ----
  short8 A1w2[3];
  f32x4 bi2;
  {
    const int zc = gl*32 + 4*w7 + (li>>2);
#pragma unroll
    for (int ks=0; ks<3; ++ks){
      short8 v1;
#pragma unroll
      for (int j=0; j<8; ++j){
        const int kk = quad*8 + j;
        float w = (ks<2) ? W2[(ks*32+kk)*128+zc] : U2[kk*128+zc];
        v1[j] = (short)rne16(w*scl);
      }
      A1w2[ks]=v1;
    }
#pragma unroll
    for (int i2=0;i2<4;++i2)
      bi2[i2] = b2[i2*32 + 4*w7 + quad] * ((i2==2)?1.0f:LOG2E);
  }

  // zero LDS
  { unsigned* p1 = (unsigned*)a1; for (int i=tid;i<2*ROWS*AS1/2;i+=1024) p1[i]=0u;
    unsigned* p2 = (unsigned*)a2; for (int i=tid;i<2*ROWS*AS2/2;i+=1024) p2[i]=0u;
    unsigned* p3 = (unsigned*)a3; for (int i=tid;i<2*ROWS*AS3/2;i+=1024) p3[i]=0u; }
  __syncthreads();
  // stage x(0) into slot 0
  if (tid < ROWS*FF){
    const int r = tid/FF, f = tid - r*FF;
    a1[0][r*AS1 + 64 + f] = rne16(x[((size_t)(b0+r)*TT + 0)*FF + f]);
  }
  // x prefetch: va=x(1), vb=x(2)
  int pr=0, pf=0; const float* xp=nullptr;
  float va=0.f, vb=0.f;
  const bool st = (tid < ROWS*FF);
  if (st){
    pr = tid/FF; pf = tid - pr*FF;
    xp = x + (size_t)(b0+pr)*TT*FF + pf;
    va = xp[1*FF];
    vb = xp[2*FF];
  }
  float c1s[2] = {0.f,0.f};
  float c2s = 0.f;
  const int rb1 = arow*AS1;
  const int rb2 = arow*AS2;
  const int hw1p = rb1 + 8*w7 + 2*quad;
  const int hw2 = rb2 + 4*w7 + quad;
  __syncthreads();

  // =================== loop A: L1 + L2, role-split ===================
  f32x4 Cl1a, Cl1b, Cl2;   // parked MFMA results (M-phase -> G-phase)
#pragma unroll 1
  for (int p = 0; p <= 2*TT+2; ++p){
    if (((p ^ rg) & 1) == 0){
      // ---- M-phase: read frags + MFMA, park C ----
      const int mt = (p - rg) >> 1;
      if (mt <= TT){
        const int s = mt & 1;
        short8 Bh0 = *(const short8*)&a1[s][rb1 +      quad*8];
        short8 Bh1 = *(const short8*)&a1[s][rb1 + 32 + quad*8];
        if (mt < TT){
          short8 Bx = *(const short8*)&a1[s][rb1 + 64 + quad*8];
          { f32x4 C = bi1[0];
            C = MFMA(A1w[0][0], Bh0, C);
            C = MFMA(A1w[0][1], Bh1, C);
            C = MFMA(A1w[0][2], Bx,  C); Cl1a = C; }
          { f32x4 C = bi1[1];
            C = MFMA(A1w[1][0], Bh0, C);
            C = MFMA(A1w[1][1], Bh1, C);
            C = MFMA(A1w[1][2], Bx,  C); Cl1b = C; }
        }
        if (mt >= 1){
          f32x4 C = bi2;
          C = MFMA(A1w2[0], Bh0, C);
          C = MFMA(A1w2[1], Bh1, C);
          short8 Bh2 = *(const short8*)&a2[s][rb2 + quad*8];
          C = MFMA(A1w2[2], Bh2, C);
          Cl2 = C;
        }
      }
    } else {
      // ---- G-phase: gates on parked C + writes ----
      const int gt = (p - rg - 1) >> 1;
      if (gt >= 0 && gt <= TT){
        const int ns = (gt & 1) ^ 1;
        if (gt < TT){
          float hp[2];
          { f32x4 C = Cl1a;
            const float ig = sig2(C[0]), fg = sig2(C[1]);
            const float gg = fmaxf(C[2],0.f), og = sig2(C[3]);
            const float cn = fg*c1s[0] + ig*gg; c1s[0] = cn;
            hp[0] = og*fmaxf(cn,0.f); }
          { f32x4 C = Cl1b;
            const float ig = sig2(C[0]), fg = sig2(C[1]);
            const float gg = fmaxf(C[2],0.f), og = sig2(C[3]);
            const float cn = fg*c1s[1] + ig*gg; c1s[1] = cn;
            hp[1] = og*fmaxf(cn,0.f); }
          *(unsigned*)&a1[ns][hw1p] = cvtpk(hp[0], hp[1]);
        }
        if (gt >= 1){
          f32x4 C = Cl2;
          const float ig = sig2(C[0]), fg = sig2(C[1]);
          const float gg = fmaxf(C[2],0.f), og = sig2(C[3]);
          const float cn = fg*c2s + ig*gg; c2s = cn;
          const float h = og*fmaxf(cn,0.f);
          a2[ns][hw2] = (unsigned short)cvtpk(h, h);  // gt==TT -> a2[1] final
        }
      }
    }
    // ---- x staging: even phases only; x(tx) -> slot tx&1 ----
    if (((p & 1) == 0) && st){
      const int tx = (p >> 1) + 1;
      if (tx < TT){
        a1[tx&1][pr*AS1 + 64 + pf] = (unsigned short)cvtpk(va, va);
        va = vb;
        if (tx+2 < TT) vb = xp[(tx+2)*FF];
      }
    }
    phase_barrier();
  }

  // =================== prologue C: L3 + dense weights ===================
  short8 A1u[2][2];
  short8 A1w3[2];
  f32x4 bi3[2];
#pragma unroll
  for (int tp=0; tp<2; ++tp){
    const int zc = gl*64 + 8*w7 + 2*(li>>2) + tp;
#pragma unroll
    for (int ks=0; ks<2; ++ks){
      short8 v1;
#pragma unroll
      for (int j=0; j<8; ++j){
        const int k = ks*32 + quad*8 + j;
        v1[j] = (short)rne16(U3[k*256+zc]*scl);
      }
      A1u[tp][ks]=v1;
    }
    {
      short8 v1;
#pragma unroll
      for (int j=0; j<8; ++j){
        const int k = quad*8 + j;
        v1[j] = (short)rne16(W3[k*256+zc]*scl);
      }
      A1w3[tp]=v1;
    }
#pragma unroll
    for (int i2=0;i2<4;++i2)
      bi3[tp][i2] = b3[i2*64 + 8*w7 + 2*quad + tp] * ((i2==2)?1.0f:LOG2E);
  }
  const bool dW = (w7 < 2);
  const int dcol = w7*16 + li;
  const bool dOK = dW && (dcol < 24);
  const float bdv = dOK ? bd[dcol] : 0.f;
  short8 Bd1[2];
  if (dW){
#pragma unroll
    for (int ks=0; ks<2; ++ks){
      short8 v1;
#pragma unroll
      for (int j=0; j<8; ++j){
        const int k = ks*32 + quad*8 + j;
        v1[j] = (short)rne16(dOK ? Wd[k*24+dcol] : 0.f);
      }
      Bd1[ks]=v1;
    }
  }

  // ZR = b3 + h2@W3 (h2 bf16 in a2[1])
  f32x4 zr[2];
  {
    short8 Ba = *(const short8*)&a2[1][rb2 + quad*8];
#pragma unroll
    for (int tp=0; tp<2; ++tp){
      f32x4 C = bi3[tp];
      C = MFMA(A1w3[tp], Ba, C);
      zr[tp] = C;
    }
  }
  float c3s[2] = {0.f,0.f};
  const int rb3 = arow*AS3;
  const int hw3p = rb3 + 8*w7 + 2*quad;
  __syncthreads();

  // =================== loop C: L3 + fused dense, role-split ===================
  f32x4 Cl3a, Cl3b;
#pragma unroll 1
  for (int p = 0; p <= 2*TT+1; ++p){
    if (((p ^ rg) & 1) == 0){
      // ---- M-phase: read h3 frags, MFMA z3(mt) + dense(mt-1) ----
      const int mt = (p - rg) >> 1;
      if (mt <= TT){
        const int s = mt & 1;
        short8 Ba0 = *(const short8*)&a3[s][rb3 +      quad*8];
        short8 Ba1 = *(const short8*)&a3[s][rb3 + 32 + quad*8];
        if (mt < TT){
          { f32x4 C = zr[0];
            C = MFMA(A1u[0][0], Ba0, C);
            C = MFMA(A1u[0][1], Ba1, C); Cl3a = C; }
          { f32x4 C = zr[1];
            C = MFMA(A1u[1][0], Ba0, C);
            C = MFMA(A1u[1][1], Ba1, C); Cl3b = C; }
        }
        if (dW && mt > 0){
          f32x4 Cd = {bdv,bdv,bdv,bdv};
          Cd = MFMA(Ba0, Bd1[0], Cd);
          Cd = MFMA(Ba1, Bd1[1], Cd);
          if (dcol < 24){
#pragma unroll
            for (int i2=0;i2<4;++i2)
              out[((size_t)(b0+rg*16+quad*4+i2)*TT + (mt-1))*FF + dcol] = Cd[i2];
          }
        }
      }
    } else {
      // ---- G-phase: gates on parked C + h3 write ----
      const int gt = (p - rg - 1) >> 1;
      if (gt >= 0 && gt < TT){
        const int ns = (gt & 1) ^ 1;
        float hp[2];
        { f32x4 C = Cl3a;
          const float ig = sig2(C[0]), fg = sig2(C[1]);
          const float gg = fmaxf(C[2],0.f), og = sig2(C[3]);
          const float cn = fg*c3s[0] + ig*gg; c3s[0] = cn;
          hp[0] = og*fmaxf(cn,0.f); }
        { f32x4 C = Cl3b;
          const float ig = sig2(C[0]), fg = sig2(C[1]);
          const float gg = fmaxf(C[2],0.f), og = sig2(C[3]);
          const float cn = fg*c3s[1] + ig*gg; c3s[1] = cn;
          hp[1] = og*fmaxf(cn,0.f); }
        *(unsigned*)&a3[ns][hw3p] = cvtpk(hp[0], hp[1]);
      }
    }
    phase_barrier();
  }
}

extern "C" void kernel_launch(void* const* d_in, const int* in_sizes, int n_in,
                              void* d_out, int out_size, void* d_ws, size_t ws_size,
                              hipStream_t stream){
  const float* x  = (const float*)d_in[0];
  const float* W1 = (const float*)d_in[1];
  const float* U1 = (const float*)d_in[2];
  const float* b1 = (const float*)d_in[3];
  const float* W2 = (const float*)d_in[4];
  const float* U2 = (const float*)d_in[5];
  const float* b2 = (const float*)d_in[6];
  const float* W3 = (const float*)d_in[7];
  const float* U3 = (const float*)d_in[8];
  const float* b3 = (const float*)d_in[9];
  const float* Wd = (const float*)d_in[10];
  const float* bd = (const float*)d_in[11];
  float* out = (float*)d_out;

  hipLaunchKernelGGL(ae_fused, dim3(BB/ROWS), dim3(1024), 0, stream,
                     x, W1, U1, b1, W2, U2, b2, W3, U3, b3, Wd, bd, out);
}